// Round 1
// 240.994 us; speedup vs baseline: 1.1382x; 1.1382x over previous
//
#include <hip/hip_runtime.h>

#define NN 4096
#define CC 32
#define TT 12
#define BB 4
#define BT 48          // BB*TT
#define NC 1536        // BT*CC
#define MAXD 192       // mean degree ~82; P(deg>192) astronomically small
#define FW 512         // features per chunk (8/lane, 16B); chunk slice = 4096*1KB = 4MB
#define NCH 3          // NC / FW
#define STP 36         // k_trans LDS row stride (ushorts)
#define SOP 33         // k_mix LDS row stride (floats)

typedef float f32x4 __attribute__((ext_vector_type(4)));
typedef short short8 __attribute__((ext_vector_type(8)));
typedef unsigned short ushort8 __attribute__((ext_vector_type(8)));

__device__ __forceinline__ float bf2f(unsigned short h) {
  return __uint_as_float(((unsigned int)h) << 16);
}
__device__ __forceinline__ unsigned short f2bf(float f) {
  unsigned int u = __float_as_uint(f);
  return (unsigned short)((u + 0x7FFFu + ((u >> 16) & 1u)) >> 16);  // RNE
}
__device__ __forceinline__ float blo(unsigned int w) { return __uint_as_float(w << 16); }
__device__ __forceinline__ float bhi(unsigned int w) { return __uint_as_float(w & 0xFFFF0000u); }

// ---- adjacency (fp32) compaction into edges[].x + degree + d^-1/2
__global__ __launch_bounds__(256) void k_build(const float* __restrict__ adj,
                                               uint2* __restrict__ edges,
                                               int* __restrict__ deg, float* __restrict__ dis) {
  __shared__ int cnt;
  int m = blockIdx.x;
  if (threadIdx.x == 0) cnt = 0;
  __syncthreads();
  unsigned int* ecol = (unsigned int*)(edges + m * MAXD);
  const uint4* row = (const uint4*)(adj + (size_t)m * NN);
  for (int i = threadIdx.x; i < NN / 4; i += 256) {
    uint4 v = row[i];
    unsigned int ws[4] = {v.x, v.y, v.z, v.w};
    #pragma unroll
    for (int k = 0; k < 4; ++k) {
      if (ws[k] != 0) {
        int p = atomicAdd(&cnt, 1);
        if (p < MAXD) ecol[p * 2] = (unsigned int)(i * 4 + k);
      }
    }
  }
  __syncthreads();
  if (threadIdx.x == 0) {
    int d = cnt < MAXD ? cnt : MAXD;
    deg[m] = d;
    dis[m] = d > 0 ? (float)(1.0 / sqrt((double)d)) : 0.0f;
  }
}

// ---- edges[].y = dis[col]; pad edge list to multiple of 16 with {m, 0} dummies.
__global__ __launch_bounds__(192) void k_wt(uint2* __restrict__ edges,
                                            const int* __restrict__ deg,
                                            int* __restrict__ degp,
                                            const float* __restrict__ dis) {
  int m = blockIdx.x;
  int j = threadIdx.x;
  int d = deg[m];
  int dp = (d + 15) & ~15;
  if (j < d) {
    unsigned int* e = (unsigned int*)(edges + m * MAXD + j);
    e[1] = __float_as_uint(dis[e[0]]);
  } else if (j < dp) {
    edges[m * MAXD + j] = make_uint2((unsigned int)m, 0u);  // weight 0.0f
  }
  if (j == 0) degp[m] = dp;
}

// ---- x[b][c][n][t] (fp32) -> H[n][bt][c] (bf16) via LDS transpose; coalesced both sides.
__global__ __launch_bounds__(256) void k_trans(const float* __restrict__ x,
                                               unsigned short* __restrict__ H) {
  __shared__ unsigned short sT[192 * STP];
  int b = blockIdx.x >> 8;
  int n0 = (blockIdx.x & 255) * 16;
  int c = threadIdx.x >> 3;        // 32 c-groups
  int l8 = threadIdx.x & 7;
  size_t base = ((size_t)(b * CC + c) * NN + n0) * TT;  // 192 contiguous floats per (b,c)
  #pragma unroll
  for (int it = 0; it < 6; ++it) {
    int j0 = it * 32 + l8 * 4;                 // j = nl*12 + t
    float4 f = *(const float4*)(x + base + j0);
    sT[(j0 + 0) * STP + c] = f2bf(f.x);
    sT[(j0 + 1) * STP + c] = f2bf(f.y);
    sT[(j0 + 2) * STP + c] = f2bf(f.z);
    sT[(j0 + 3) * STP + c] = f2bf(f.w);
  }
  __syncthreads();
  #pragma unroll
  for (int k = 0; k < 6; ++k) {
    int p = (threadIdx.x >> 3) + 32 * k;       // 192 (nl,t) runs
    int nl = p / TT, t = p - nl * TT;
    ushort4 v = *(const ushort4*)&sT[p * STP + l8 * 4];
    size_t off = ((size_t)(n0 + nl) * BT + b * TT + t) * CC + l8 * 4;
    *(ushort4*)(H + off) = v;
  }
}

// ---- pure gather: D[m,q] = dis[m] * sum_e dis[col]*S[col,q]   (= (A' S)[m,q])
// grid (NN/4, NCH); wave wid owns node bx*4+wid; 16B/lane covers 512 features.
// Load-phase into uint4 hv[8] FORCES 8 outstanding 16B loads (the old unroll-16
// collapsed to VGPR=28 => ~no MLP); compute-phase then drains them.
__global__ __launch_bounds__(256) void k_gather(const unsigned short* __restrict__ S,
                                                const uint2* __restrict__ edges,
                                                const int* __restrict__ degp,
                                                const float* __restrict__ dis,
                                                unsigned short* __restrict__ D) {
  int wid = __builtin_amdgcn_readfirstlane(threadIdx.x >> 6);
  int lane = threadIdx.x & 63;
  int m = blockIdx.x * 4 + wid;
  int d = degp[m];                      // padded to x16
  float dm = dis[m];
  const uint2* ep = edges + m * MAXD;
  int fo = blockIdx.y * FW + lane * 8;
  const unsigned short* Sf = S + fo;
  float a0 = 0.f, a1 = 0.f, a2 = 0.f, a3 = 0.f;
  float a4 = 0.f, a5 = 0.f, a6 = 0.f, a7 = 0.f;
  for (int e = 0; e < d; e += 8) {
    uint4 hv[8];
    float w[8];
    #pragma unroll
    for (int k = 0; k < 8; ++k) {
      uint2 ew = ep[e + k];             // wave-uniform -> batched s_loads
      w[k] = __uint_as_float(ew.y);
      hv[k] = *(const uint4*)(Sf + (int)ew.x * NC);
    }
    #pragma unroll
    for (int k = 0; k < 8; ++k) {
      float wk = w[k];
      a0 = fmaf(wk, blo(hv[k].x), a0); a1 = fmaf(wk, bhi(hv[k].x), a1);
      a2 = fmaf(wk, blo(hv[k].y), a2); a3 = fmaf(wk, bhi(hv[k].y), a3);
      a4 = fmaf(wk, blo(hv[k].z), a4); a5 = fmaf(wk, bhi(hv[k].z), a5);
      a6 = fmaf(wk, blo(hv[k].w), a6); a7 = fmaf(wk, bhi(hv[k].w), a7);
    }
  }
  ushort8 o;
  o[0] = f2bf(dm * a0); o[1] = f2bf(dm * a1);
  o[2] = f2bf(dm * a2); o[3] = f2bf(dm * a3);
  o[4] = f2bf(dm * a4); o[5] = f2bf(dm * a5);
  o[6] = f2bf(dm * a6); o[7] = f2bf(dm * a7);
  *(ushort8*)(D + (size_t)m * NC + fo) = o;
}

// ---- MFMA channel mix in G-basis:
// out = H*(W0+W1+W2) + G1*(-W1-4W2) + G2*(2W2) + bias   (T1=H-G1, T2=H-4G1+2G2)
__global__ __launch_bounds__(256) void k_mix(const unsigned short* __restrict__ H,
                                             const unsigned short* __restrict__ G1,
                                             const unsigned short* __restrict__ G2,
                                             const float* __restrict__ W,
                                             const float* __restrict__ bias,
                                             float* __restrict__ out) {
  __shared__ __align__(16) float sOut[192 * SOP];
  int wid = threadIdx.x >> 6, lane = threadIdx.x & 63;
  int lm = lane & 15, quad = lane >> 4;
  short8 bhf[2][3], blf[2][3];
  float bias0[2];
  for (int h = 0; h < 2; ++h)
    for (int g = 0; g < 3; ++g) {
      short8 vh, vl;
      #pragma unroll
      for (int j = 0; j < 8; ++j) {
        int r = quad * 8 + j, c = h * 16 + lm;
        float w0 = W[(0 * CC + r) * CC + c];
        float w1 = W[(1 * CC + r) * CC + c];
        float w2 = W[(2 * CC + r) * CC + c];
        float w = (g == 0) ? (w0 + w1 + w2)
                 : (g == 1) ? (-w1 - 4.f * w2)
                            : (2.f * w2);
        unsigned short hi = f2bf(w);
        vh[j] = (short)hi;
        vl[j] = (short)f2bf(w - bf2f(hi));
      }
      bhf[h][g] = vh; blf[h][g] = vl;
    }
  #pragma unroll
  for (int h = 0; h < 2; ++h) bias0[h] = bias[h * 16 + lm];
  int n0 = blockIdx.x * 4;
  #pragma unroll
  for (int tI = 0; tI < 3; ++tI) {
    int r0l = wid * BT + tI * 16;
    size_t abase = ((size_t)(n0 * BT) + r0l + lm) * CC + quad * 8;
    short8 af0 = *(const short8*)(H + abase);
    short8 af1 = *(const short8*)(G1 + abase);
    short8 af2 = *(const short8*)(G2 + abase);
    #pragma unroll
    for (int h = 0; h < 2; ++h) {
      f32x4 acc = {bias0[h], bias0[h], bias0[h], bias0[h]};
      acc = __builtin_amdgcn_mfma_f32_16x16x32_bf16(af0, bhf[h][0], acc, 0, 0, 0);
      acc = __builtin_amdgcn_mfma_f32_16x16x32_bf16(af0, blf[h][0], acc, 0, 0, 0);
      acc = __builtin_amdgcn_mfma_f32_16x16x32_bf16(af1, bhf[h][1], acc, 0, 0, 0);
      acc = __builtin_amdgcn_mfma_f32_16x16x32_bf16(af1, blf[h][1], acc, 0, 0, 0);
      acc = __builtin_amdgcn_mfma_f32_16x16x32_bf16(af2, bhf[h][2], acc, 0, 0, 0);
      acc = __builtin_amdgcn_mfma_f32_16x16x32_bf16(af2, blf[h][2], acc, 0, 0, 0);
      int o = h * 16 + lm;
      #pragma unroll
      for (int reg = 0; reg < 4; ++reg)
        sOut[(r0l + quad * 4 + reg) * SOP + o] = acc[reg];
    }
  }
  __syncthreads();
  #pragma unroll
  for (int j = 0; j < 6; ++j) {
    int idx = j * 256 + threadIdx.x;
    int bo = idx / 12;                  // b*32 + o
    int fq = idx - bo * 12;
    int p0 = fq * 4;                    // elem within the 48-long (b,o) run
    float v[4];
    #pragma unroll
    for (int k = 0; k < 4; ++k) {
      int p = p0 + k;
      int nl = p / TT, t = p - nl * TT;
      int b = bo >> 5, o = bo & 31;
      v[k] = sOut[(nl * BT + b * TT + t) * SOP + o];
    }
    size_t base = (((size_t)bo * NN) + n0) * TT + p0;
    *(float4*)(out + base) = make_float4(v[0], v[1], v[2], v[3]);
  }
}

extern "C" void kernel_launch(void* const* d_in, const int* in_sizes, int n_in,
                              void* d_out, int out_size, void* d_ws, size_t ws_size,
                              hipStream_t stream) {
  const float* x    = (const float*)d_in[0];
  const float* adj  = (const float*)d_in[1];
  const float* wgt  = (const float*)d_in[2];
  const float* bias = (const float*)d_in[3];
  char* ws = (char*)d_ws;
  float* dis  = (float*)ws;                                 // 16 KB
  int*   deg  = (int*)(ws + 16384);                         // 16 KB
  int*   degp = (int*)(ws + 32768);                         // 16 KB
  uint2* edges = (uint2*)(ws + 49152);                      // 6.29 MB
  char* p = ws + 49152 + (size_t)NN * MAXD * 8;
  unsigned short* H  = (unsigned short*)p;                  // 12.58 MB
  unsigned short* G1 = (unsigned short*)(p + (size_t)NN * NC * 2);
  unsigned short* G2 = (unsigned short*)(p + (size_t)NN * NC * 4);

  k_build<<<NN, 256, 0, stream>>>(adj, edges, deg, dis);
  k_wt<<<NN, 192, 0, stream>>>(edges, deg, degp, dis);
  k_trans<<<1024, 256, 0, stream>>>(x, H);
  k_gather<<<dim3(NN / 4, NCH), 256, 0, stream>>>(H, edges, degp, dis, G1);
  k_gather<<<dim3(NN / 4, NCH), 256, 0, stream>>>(G1, edges, degp, dis, G2);
  k_mix<<<NN / 4, 256, 0, stream>>>(H, G1, G2, wgt, bias, (float*)d_out);
}

// Round 2
// 239.799 us; speedup vs baseline: 1.1439x; 1.0050x over previous
//
#include <hip/hip_runtime.h>

#define NN 4096
#define CC 32
#define TT 12
#define BB 4
#define BT 48          // BB*TT
#define NC 1536        // BT*CC
#define MAXD 192       // mean degree ~82; P(deg>192) astronomically small
#define FW 512         // features per chunk (8/lane, 16B); chunk slice = 4096*1KB = 4MB
#define NCH 3          // NC / FW
#define STP 36         // k_trans LDS row stride (ushorts)
#define SOP 33         // k_mix LDS row stride (floats)

typedef float f32x4 __attribute__((ext_vector_type(4)));
typedef short short8 __attribute__((ext_vector_type(8)));
typedef unsigned short ushort8 __attribute__((ext_vector_type(8)));

__device__ __forceinline__ float bf2f(unsigned short h) {
  return __uint_as_float(((unsigned int)h) << 16);
}
__device__ __forceinline__ unsigned short f2bf(float f) {
  unsigned int u = __float_as_uint(f);
  return (unsigned short)((u + 0x7FFFu + ((u >> 16) & 1u)) >> 16);  // RNE
}
__device__ __forceinline__ float blo(unsigned int w) { return __uint_as_float(w << 16); }
__device__ __forceinline__ float bhi(unsigned int w) { return __uint_as_float(w & 0xFFFF0000u); }

// ---- adjacency (fp32) compaction into edges[].x + degree + d^-1/2
__global__ __launch_bounds__(256) void k_build(const float* __restrict__ adj,
                                               uint2* __restrict__ edges,
                                               int* __restrict__ deg, float* __restrict__ dis) {
  __shared__ int cnt;
  int m = blockIdx.x;
  if (threadIdx.x == 0) cnt = 0;
  __syncthreads();
  unsigned int* ecol = (unsigned int*)(edges + m * MAXD);
  const uint4* row = (const uint4*)(adj + (size_t)m * NN);
  for (int i = threadIdx.x; i < NN / 4; i += 256) {
    uint4 v = row[i];
    unsigned int ws[4] = {v.x, v.y, v.z, v.w};
    #pragma unroll
    for (int k = 0; k < 4; ++k) {
      if (ws[k] != 0) {
        int p = atomicAdd(&cnt, 1);
        if (p < MAXD) ecol[p * 2] = (unsigned int)(i * 4 + k);
      }
    }
  }
  __syncthreads();
  if (threadIdx.x == 0) {
    int d = cnt < MAXD ? cnt : MAXD;
    deg[m] = d;
    dis[m] = d > 0 ? (float)(1.0 / sqrt((double)d)) : 0.0f;
  }
}

// ---- edges[].y = dis[col]; pad edge list to multiple of 16 with {m, 0} dummies.
__global__ __launch_bounds__(192) void k_wt(uint2* __restrict__ edges,
                                            const int* __restrict__ deg,
                                            int* __restrict__ degp,
                                            const float* __restrict__ dis) {
  int m = blockIdx.x;
  int j = threadIdx.x;
  int d = deg[m];
  int dp = (d + 15) & ~15;
  if (j < d) {
    unsigned int* e = (unsigned int*)(edges + m * MAXD + j);
    e[1] = __float_as_uint(dis[e[0]]);
  } else if (j < dp) {
    edges[m * MAXD + j] = make_uint2((unsigned int)m, 0u);  // weight 0.0f
  }
  if (j == 0) degp[m] = dp;
}

// ---- x[b][c][n][t] (fp32) -> H[n][bt][c] (bf16) via LDS transpose; coalesced both sides.
__global__ __launch_bounds__(256) void k_trans(const float* __restrict__ x,
                                               unsigned short* __restrict__ H) {
  __shared__ unsigned short sT[192 * STP];
  int b = blockIdx.x >> 8;
  int n0 = (blockIdx.x & 255) * 16;
  int c = threadIdx.x >> 3;        // 32 c-groups
  int l8 = threadIdx.x & 7;
  size_t base = ((size_t)(b * CC + c) * NN + n0) * TT;  // 192 contiguous floats per (b,c)
  #pragma unroll
  for (int it = 0; it < 6; ++it) {
    int j0 = it * 32 + l8 * 4;                 // j = nl*12 + t
    float4 f = *(const float4*)(x + base + j0);
    sT[(j0 + 0) * STP + c] = f2bf(f.x);
    sT[(j0 + 1) * STP + c] = f2bf(f.y);
    sT[(j0 + 2) * STP + c] = f2bf(f.z);
    sT[(j0 + 3) * STP + c] = f2bf(f.w);
  }
  __syncthreads();
  #pragma unroll
  for (int k = 0; k < 6; ++k) {
    int p = (threadIdx.x >> 3) + 32 * k;       // 192 (nl,t) runs
    int nl = p / TT, t = p - nl * TT;
    ushort4 v = *(const ushort4*)&sT[p * STP + l8 * 4];
    size_t off = ((size_t)(n0 + nl) * BT + b * TT + t) * CC + l8 * 4;
    *(ushort4*)(H + off) = v;
  }
}

// ---- pure gather: D[m,q] = dis[m] * sum_e dis[col]*S[col,q]   (= (A' S)[m,q])
// grid (NN/4, NCH); wave wid owns node bx*4+wid; 16B/lane covers 512 features.
// v2: (1) edge lists staged in LDS (broadcast ds_reads, no per-group K$/L2 stall
// on the address stream); (2) two-buffer A/B software pipeline so every payload
// group has a full compute-phase of latency cover; (3) launch_bounds(256,4) ->
// 4 blocks/CU, grid 3072 = exactly 3 residency rounds.
__global__ __launch_bounds__(256, 4) void k_gather(const unsigned short* __restrict__ S,
                                                   const uint2* __restrict__ edges,
                                                   const int* __restrict__ degp,
                                                   const float* __restrict__ dis,
                                                   unsigned short* __restrict__ D) {
  __shared__ uint2 sE[4 * MAXD];                // 6 KB: 4 nodes x 192 edges
  int tid = threadIdx.x;
  int bx = blockIdx.x;
  {
    const uint2* src = edges + (size_t)bx * 4 * MAXD;
    #pragma unroll
    for (int i = 0; i < 3; ++i) sE[tid + 256 * i] = src[tid + 256 * i];
  }
  __syncthreads();
  int wid = __builtin_amdgcn_readfirstlane(tid >> 6);
  int lane = tid & 63;
  int m = bx * 4 + wid;
  int d = degp[m];                      // padded to x16 -> ng even, >=2 (or 0)
  float dm = dis[m];
  const uint2* ep = sE + wid * MAXD;
  int fo = blockIdx.y * FW + lane * 8;
  const unsigned short* Sf = S + fo;
  float a0 = 0.f, a1 = 0.f, a2 = 0.f, a3 = 0.f;
  float a4 = 0.f, a5 = 0.f, a6 = 0.f, a7 = 0.f;

  auto LOADG = [&](uint4* hv, float* w, int e) {
    #pragma unroll
    for (int k = 0; k < 8; ++k) {
      uint2 ew = ep[e + k];             // LDS broadcast (wave-uniform addr)
      w[k] = __uint_as_float(ew.y);
      hv[k] = *(const uint4*)(Sf + (int)ew.x * NC);
    }
  };
  auto COMPUTE = [&](const uint4* hv, const float* w) {
    #pragma unroll
    for (int k = 0; k < 8; ++k) {
      float wk = w[k];
      a0 = fmaf(wk, blo(hv[k].x), a0); a1 = fmaf(wk, bhi(hv[k].x), a1);
      a2 = fmaf(wk, blo(hv[k].y), a2); a3 = fmaf(wk, bhi(hv[k].y), a3);
      a4 = fmaf(wk, blo(hv[k].z), a4); a5 = fmaf(wk, bhi(hv[k].z), a5);
      a6 = fmaf(wk, blo(hv[k].w), a6); a7 = fmaf(wk, bhi(hv[k].w), a7);
    }
  };

  if (d) {
    int ng = d >> 3;                    // even, >= 2
    uint4 A[8], B[8];
    float wA[8], wB[8];
    LOADG(A, wA, 0);
    LOADG(B, wB, 8);
    int g = 0;
    for (; g + 2 < ng; g += 2) {
      COMPUTE(A, wA);                   // B in flight, issued 1 phase ago
      LOADG(A, wA, (g + 2) * 8);        // refill A for g+2
      COMPUTE(B, wB);                   // A(g+2) in flight
      LOADG(B, wB, (g + 3) * 8);        // refill B for g+3 (g+3 <= ng-1 here)
    }
    COMPUTE(A, wA);
    COMPUTE(B, wB);
  }
  ushort8 o;
  o[0] = f2bf(dm * a0); o[1] = f2bf(dm * a1);
  o[2] = f2bf(dm * a2); o[3] = f2bf(dm * a3);
  o[4] = f2bf(dm * a4); o[5] = f2bf(dm * a5);
  o[6] = f2bf(dm * a6); o[7] = f2bf(dm * a7);
  *(ushort8*)(D + (size_t)m * NC + fo) = o;
}

// ---- MFMA channel mix in G-basis:
// out = H*(W0+W1+W2) + G1*(-W1-4W2) + G2*(2W2) + bias   (T1=H-G1, T2=H-4G1+2G2)
__global__ __launch_bounds__(256) void k_mix(const unsigned short* __restrict__ H,
                                             const unsigned short* __restrict__ G1,
                                             const unsigned short* __restrict__ G2,
                                             const float* __restrict__ W,
                                             const float* __restrict__ bias,
                                             float* __restrict__ out) {
  __shared__ __align__(16) float sOut[192 * SOP];
  int wid = threadIdx.x >> 6, lane = threadIdx.x & 63;
  int lm = lane & 15, quad = lane >> 4;
  short8 bhf[2][3], blf[2][3];
  float bias0[2];
  for (int h = 0; h < 2; ++h)
    for (int g = 0; g < 3; ++g) {
      short8 vh, vl;
      #pragma unroll
      for (int j = 0; j < 8; ++j) {
        int r = quad * 8 + j, c = h * 16 + lm;
        float w0 = W[(0 * CC + r) * CC + c];
        float w1 = W[(1 * CC + r) * CC + c];
        float w2 = W[(2 * CC + r) * CC + c];
        float w = (g == 0) ? (w0 + w1 + w2)
                 : (g == 1) ? (-w1 - 4.f * w2)
                            : (2.f * w2);
        unsigned short hi = f2bf(w);
        vh[j] = (short)hi;
        vl[j] = (short)f2bf(w - bf2f(hi));
      }
      bhf[h][g] = vh; blf[h][g] = vl;
    }
  #pragma unroll
  for (int h = 0; h < 2; ++h) bias0[h] = bias[h * 16 + lm];
  int n0 = blockIdx.x * 4;
  #pragma unroll
  for (int tI = 0; tI < 3; ++tI) {
    int r0l = wid * BT + tI * 16;
    size_t abase = ((size_t)(n0 * BT) + r0l + lm) * CC + quad * 8;
    short8 af0 = *(const short8*)(H + abase);
    short8 af1 = *(const short8*)(G1 + abase);
    short8 af2 = *(const short8*)(G2 + abase);
    #pragma unroll
    for (int h = 0; h < 2; ++h) {
      f32x4 acc = {bias0[h], bias0[h], bias0[h], bias0[h]};
      acc = __builtin_amdgcn_mfma_f32_16x16x32_bf16(af0, bhf[h][0], acc, 0, 0, 0);
      acc = __builtin_amdgcn_mfma_f32_16x16x32_bf16(af0, blf[h][0], acc, 0, 0, 0);
      acc = __builtin_amdgcn_mfma_f32_16x16x32_bf16(af1, bhf[h][1], acc, 0, 0, 0);
      acc = __builtin_amdgcn_mfma_f32_16x16x32_bf16(af1, blf[h][1], acc, 0, 0, 0);
      acc = __builtin_amdgcn_mfma_f32_16x16x32_bf16(af2, bhf[h][2], acc, 0, 0, 0);
      acc = __builtin_amdgcn_mfma_f32_16x16x32_bf16(af2, blf[h][2], acc, 0, 0, 0);
      int o = h * 16 + lm;
      #pragma unroll
      for (int reg = 0; reg < 4; ++reg)
        sOut[(r0l + quad * 4 + reg) * SOP + o] = acc[reg];
    }
  }
  __syncthreads();
  #pragma unroll
  for (int j = 0; j < 6; ++j) {
    int idx = j * 256 + threadIdx.x;
    int bo = idx / 12;                  // b*32 + o
    int fq = idx - bo * 12;
    int p0 = fq * 4;                    // elem within the 48-long (b,o) run
    float v[4];
    #pragma unroll
    for (int k = 0; k < 4; ++k) {
      int p = p0 + k;
      int nl = p / TT, t = p - nl * TT;
      int b = bo >> 5, o = bo & 31;
      v[k] = sOut[(nl * BT + b * TT + t) * SOP + o];
    }
    size_t base = (((size_t)bo * NN) + n0) * TT + p0;
    *(float4*)(out + base) = make_float4(v[0], v[1], v[2], v[3]);
  }
}

extern "C" void kernel_launch(void* const* d_in, const int* in_sizes, int n_in,
                              void* d_out, int out_size, void* d_ws, size_t ws_size,
                              hipStream_t stream) {
  const float* x    = (const float*)d_in[0];
  const float* adj  = (const float*)d_in[1];
  const float* wgt  = (const float*)d_in[2];
  const float* bias = (const float*)d_in[3];
  char* ws = (char*)d_ws;
  float* dis  = (float*)ws;                                 // 16 KB
  int*   deg  = (int*)(ws + 16384);                         // 16 KB
  int*   degp = (int*)(ws + 32768);                         // 16 KB
  uint2* edges = (uint2*)(ws + 49152);                      // 6.29 MB
  char* p = ws + 49152 + (size_t)NN * MAXD * 8;
  unsigned short* H  = (unsigned short*)p;                  // 12.58 MB
  unsigned short* G1 = (unsigned short*)(p + (size_t)NN * NC * 2);
  unsigned short* G2 = (unsigned short*)(p + (size_t)NN * NC * 4);

  k_build<<<NN, 256, 0, stream>>>(adj, edges, deg, dis);
  k_wt<<<NN, 192, 0, stream>>>(edges, deg, degp, dis);
  k_trans<<<1024, 256, 0, stream>>>(x, H);
  k_gather<<<dim3(NN / 4, NCH), 256, 0, stream>>>(H, edges, degp, dis, G1);
  k_gather<<<dim3(NN / 4, NCH), 256, 0, stream>>>(G1, edges, degp, dis, G2);
  k_mix<<<NN / 4, 256, 0, stream>>>(H, G1, G2, wgt, bias, (float*)d_out);
}

// Round 3
// 231.833 us; speedup vs baseline: 1.1832x; 1.0344x over previous
//
#include <hip/hip_runtime.h>

#define NN 4096
#define CC 32
#define TT 12
#define BB 4
#define BT 48          // BB*TT
#define NC 1536        // BT*CC
#define MAXD 192       // mean degree ~82; P(deg>192) astronomically small
#define FW 512         // features per chunk (8/lane, 16B); chunk slice = 4096*1KB = 4MB
#define NCH 3          // NC / FW
#define STP 36         // k_trans LDS row stride (ushorts)
#define SOP 33         // k_mix LDS row stride (floats)

typedef float f32x4 __attribute__((ext_vector_type(4)));
typedef short short8 __attribute__((ext_vector_type(8)));
typedef unsigned short ushort8 __attribute__((ext_vector_type(8)));

__device__ __forceinline__ float bf2f(unsigned short h) {
  return __uint_as_float(((unsigned int)h) << 16);
}
__device__ __forceinline__ unsigned short f2bf(float f) {
  unsigned int u = __float_as_uint(f);
  return (unsigned short)((u + 0x7FFFu + ((u >> 16) & 1u)) >> 16);  // RNE
}
__device__ __forceinline__ float blo(unsigned int w) { return __uint_as_float(w << 16); }
__device__ __forceinline__ float bhi(unsigned int w) { return __uint_as_float(w & 0xFFFF0000u); }

// ---- adjacency (fp32) compaction into edges[].x + degree + d^-1/2
__global__ __launch_bounds__(256) void k_build(const float* __restrict__ adj,
                                               uint2* __restrict__ edges,
                                               int* __restrict__ deg, float* __restrict__ dis) {
  __shared__ int cnt;
  int m = blockIdx.x;
  if (threadIdx.x == 0) cnt = 0;
  __syncthreads();
  unsigned int* ecol = (unsigned int*)(edges + m * MAXD);
  const uint4* row = (const uint4*)(adj + (size_t)m * NN);
  for (int i = threadIdx.x; i < NN / 4; i += 256) {
    uint4 v = row[i];
    unsigned int ws[4] = {v.x, v.y, v.z, v.w};
    #pragma unroll
    for (int k = 0; k < 4; ++k) {
      if (ws[k] != 0) {
        int p = atomicAdd(&cnt, 1);
        if (p < MAXD) ecol[p * 2] = (unsigned int)(i * 4 + k);
      }
    }
  }
  __syncthreads();
  if (threadIdx.x == 0) {
    int d = cnt < MAXD ? cnt : MAXD;
    deg[m] = d;
    dis[m] = d > 0 ? (float)(1.0 / sqrt((double)d)) : 0.0f;
  }
}

// ---- edges[].y = dis[col]; pad edge list to multiple of 16 with {m, 0} dummies.
__global__ __launch_bounds__(192) void k_wt(uint2* __restrict__ edges,
                                            const int* __restrict__ deg,
                                            int* __restrict__ degp,
                                            const float* __restrict__ dis) {
  int m = blockIdx.x;
  int j = threadIdx.x;
  int d = deg[m];
  int dp = (d + 15) & ~15;
  if (j < d) {
    unsigned int* e = (unsigned int*)(edges + m * MAXD + j);
    e[1] = __float_as_uint(dis[e[0]]);
  } else if (j < dp) {
    edges[m * MAXD + j] = make_uint2((unsigned int)m, 0u);  // weight 0.0f
  }
  if (j == 0) degp[m] = dp;
}

// ---- x[b][c][n][t] (fp32) -> H[n][bt][c] (bf16) via LDS transpose; coalesced both sides.
__global__ __launch_bounds__(256) void k_trans(const float* __restrict__ x,
                                               unsigned short* __restrict__ H) {
  __shared__ unsigned short sT[192 * STP];
  int b = blockIdx.x >> 8;
  int n0 = (blockIdx.x & 255) * 16;
  int c = threadIdx.x >> 3;        // 32 c-groups
  int l8 = threadIdx.x & 7;
  size_t base = ((size_t)(b * CC + c) * NN + n0) * TT;  // 192 contiguous floats per (b,c)
  #pragma unroll
  for (int it = 0; it < 6; ++it) {
    int j0 = it * 32 + l8 * 4;                 // j = nl*12 + t
    float4 f = *(const float4*)(x + base + j0);
    sT[(j0 + 0) * STP + c] = f2bf(f.x);
    sT[(j0 + 1) * STP + c] = f2bf(f.y);
    sT[(j0 + 2) * STP + c] = f2bf(f.z);
    sT[(j0 + 3) * STP + c] = f2bf(f.w);
  }
  __syncthreads();
  #pragma unroll
  for (int k = 0; k < 6; ++k) {
    int p = (threadIdx.x >> 3) + 32 * k;       // 192 (nl,t) runs
    int nl = p / TT, t = p - nl * TT;
    ushort4 v = *(const ushort4*)&sT[p * STP + l8 * 4];
    size_t off = ((size_t)(n0 + nl) * BT + b * TT + t) * CC + l8 * 4;
    *(ushort4*)(H + off) = v;
  }
}

// ---- pure gather: D[m,q] = dis[m] * sum_e dis[col]*S[col,q]   (= (A' S)[m,q])
// v3: latency hidden by TLP, not per-wave ILP (compiler flattens any source
// pipeline to VGPR~48). 16-wave blocks (1024 thr), 16 nodes/block, no LDS ->
// 2 blocks/CU = 32 waves/CU residency. Edge addressing fully scalar: edge
// words s_load in 64B batches, payload = global_load_dwordx4 with uniform
// SGPR base (ew.x*NC on SALU) + constant per-lane voffset. VALU/edge = 16.
__global__ __launch_bounds__(1024) void k_gather(const unsigned short* __restrict__ S,
                                                 const uint2* __restrict__ edges,
                                                 const int* __restrict__ degp,
                                                 const float* __restrict__ dis,
                                                 unsigned short* __restrict__ D) {
  int tid = threadIdx.x;
  int wid = __builtin_amdgcn_readfirstlane(tid >> 6);
  int lane = tid & 63;
  int m = blockIdx.x * 16 + wid;
  int d = degp[m];                      // padded to x16
  float dm = dis[m];
  const uint2* ep = edges + (size_t)m * MAXD;      // wave-uniform stream
  const unsigned short* Sy = S + blockIdx.y * FW;  // uniform base
  int lo2 = lane * 8;                              // per-lane ushort offset (16B)
  float a0 = 0.f, a1 = 0.f, a2 = 0.f, a3 = 0.f;
  float a4 = 0.f, a5 = 0.f, a6 = 0.f, a7 = 0.f;
  for (int e = 0; e < d; e += 8) {
    uint4 hv[8];
    float w[8];
    #pragma unroll
    for (int k = 0; k < 8; ++k) {
      uint2 ew = ep[e + k];             // scalar (batched s_load_dwordx16)
      w[k] = __uint_as_float(ew.y);
      hv[k] = *(const uint4*)(Sy + (int)ew.x * NC + lo2);  // saddr + const voffset
    }
    #pragma unroll
    for (int k = 0; k < 8; ++k) {
      float wk = w[k];
      a0 = fmaf(wk, blo(hv[k].x), a0); a1 = fmaf(wk, bhi(hv[k].x), a1);
      a2 = fmaf(wk, blo(hv[k].y), a2); a3 = fmaf(wk, bhi(hv[k].y), a3);
      a4 = fmaf(wk, blo(hv[k].z), a4); a5 = fmaf(wk, bhi(hv[k].z), a5);
      a6 = fmaf(wk, blo(hv[k].w), a6); a7 = fmaf(wk, bhi(hv[k].w), a7);
    }
  }
  int fo = blockIdx.y * FW + lo2;
  ushort8 o;
  o[0] = f2bf(dm * a0); o[1] = f2bf(dm * a1);
  o[2] = f2bf(dm * a2); o[3] = f2bf(dm * a3);
  o[4] = f2bf(dm * a4); o[5] = f2bf(dm * a5);
  o[6] = f2bf(dm * a6); o[7] = f2bf(dm * a7);
  *(ushort8*)(D + (size_t)m * NC + fo) = o;
}

// ---- MFMA channel mix in G-basis:
// out = H*(W0+W1+W2) + G1*(-W1-4W2) + G2*(2W2) + bias   (T1=H-G1, T2=H-4G1+2G2)
__global__ __launch_bounds__(256) void k_mix(const unsigned short* __restrict__ H,
                                             const unsigned short* __restrict__ G1,
                                             const unsigned short* __restrict__ G2,
                                             const float* __restrict__ W,
                                             const float* __restrict__ bias,
                                             float* __restrict__ out) {
  __shared__ __align__(16) float sOut[192 * SOP];
  int wid = threadIdx.x >> 6, lane = threadIdx.x & 63;
  int lm = lane & 15, quad = lane >> 4;
  short8 bhf[2][3], blf[2][3];
  float bias0[2];
  for (int h = 0; h < 2; ++h)
    for (int g = 0; g < 3; ++g) {
      short8 vh, vl;
      #pragma unroll
      for (int j = 0; j < 8; ++j) {
        int r = quad * 8 + j, c = h * 16 + lm;
        float w0 = W[(0 * CC + r) * CC + c];
        float w1 = W[(1 * CC + r) * CC + c];
        float w2 = W[(2 * CC + r) * CC + c];
        float w = (g == 0) ? (w0 + w1 + w2)
                 : (g == 1) ? (-w1 - 4.f * w2)
                            : (2.f * w2);
        unsigned short hi = f2bf(w);
        vh[j] = (short)hi;
        vl[j] = (short)f2bf(w - bf2f(hi));
      }
      bhf[h][g] = vh; blf[h][g] = vl;
    }
  #pragma unroll
  for (int h = 0; h < 2; ++h) bias0[h] = bias[h * 16 + lm];
  int n0 = blockIdx.x * 4;
  #pragma unroll
  for (int tI = 0; tI < 3; ++tI) {
    int r0l = wid * BT + tI * 16;
    size_t abase = ((size_t)(n0 * BT) + r0l + lm) * CC + quad * 8;
    short8 af0 = *(const short8*)(H + abase);
    short8 af1 = *(const short8*)(G1 + abase);
    short8 af2 = *(const short8*)(G2 + abase);
    #pragma unroll
    for (int h = 0; h < 2; ++h) {
      f32x4 acc = {bias0[h], bias0[h], bias0[h], bias0[h]};
      acc = __builtin_amdgcn_mfma_f32_16x16x32_bf16(af0, bhf[h][0], acc, 0, 0, 0);
      acc = __builtin_amdgcn_mfma_f32_16x16x32_bf16(af0, blf[h][0], acc, 0, 0, 0);
      acc = __builtin_amdgcn_mfma_f32_16x16x32_bf16(af1, bhf[h][1], acc, 0, 0, 0);
      acc = __builtin_amdgcn_mfma_f32_16x16x32_bf16(af1, blf[h][1], acc, 0, 0, 0);
      acc = __builtin_amdgcn_mfma_f32_16x16x32_bf16(af2, bhf[h][2], acc, 0, 0, 0);
      acc = __builtin_amdgcn_mfma_f32_16x16x32_bf16(af2, blf[h][2], acc, 0, 0, 0);
      int o = h * 16 + lm;
      #pragma unroll
      for (int reg = 0; reg < 4; ++reg)
        sOut[(r0l + quad * 4 + reg) * SOP + o] = acc[reg];
    }
  }
  __syncthreads();
  #pragma unroll
  for (int j = 0; j < 6; ++j) {
    int idx = j * 256 + threadIdx.x;
    int bo = idx / 12;                  // b*32 + o
    int fq = idx - bo * 12;
    int p0 = fq * 4;                    // elem within the 48-long (b,o) run
    float v[4];
    #pragma unroll
    for (int k = 0; k < 4; ++k) {
      int p = p0 + k;
      int nl = p / TT, t = p - nl * TT;
      int b = bo >> 5, o = bo & 31;
      v[k] = sOut[(nl * BT + b * TT + t) * SOP + o];
    }
    size_t base = (((size_t)bo * NN) + n0) * TT + p0;
    *(float4*)(out + base) = make_float4(v[0], v[1], v[2], v[3]);
  }
}

extern "C" void kernel_launch(void* const* d_in, const int* in_sizes, int n_in,
                              void* d_out, int out_size, void* d_ws, size_t ws_size,
                              hipStream_t stream) {
  const float* x    = (const float*)d_in[0];
  const float* adj  = (const float*)d_in[1];
  const float* wgt  = (const float*)d_in[2];
  const float* bias = (const float*)d_in[3];
  char* ws = (char*)d_ws;
  float* dis  = (float*)ws;                                 // 16 KB
  int*   deg  = (int*)(ws + 16384);                         // 16 KB
  int*   degp = (int*)(ws + 32768);                         // 16 KB
  uint2* edges = (uint2*)(ws + 49152);                      // 6.29 MB
  char* p = ws + 49152 + (size_t)NN * MAXD * 8;
  unsigned short* H  = (unsigned short*)p;                  // 12.58 MB
  unsigned short* G1 = (unsigned short*)(p + (size_t)NN * NC * 2);
  unsigned short* G2 = (unsigned short*)(p + (size_t)NN * NC * 4);

  k_build<<<NN, 256, 0, stream>>>(adj, edges, deg, dis);
  k_wt<<<NN, 192, 0, stream>>>(edges, deg, degp, dis);
  k_trans<<<1024, 256, 0, stream>>>(x, H);
  k_gather<<<dim3(NN / 16, NCH), 1024, 0, stream>>>(H, edges, degp, dis, G1);
  k_gather<<<dim3(NN / 16, NCH), 1024, 0, stream>>>(G1, edges, degp, dis, G2);
  k_mix<<<NN / 4, 256, 0, stream>>>(H, G1, G2, wgt, bias, (float*)d_out);
}